// Round 1
// baseline (344.509 us; speedup 1.0000x reference)
//
#include <hip/hip_runtime.h>
#include <stdint.h>

#define BATCH 8
#define SEQ 1024
#define DMODEL 1024
#define NHEAD 16
#define HDIM 64
#define MROWS (BATCH * SEQ)   // 8192
#define NQKV (3 * DMODEL)     // 3072
// (1/sqrt(64)) * log2(e)
#define SCALE_LOG2E 0.18033688011112043f

typedef __bf16 bf16x8 __attribute__((ext_vector_type(8)));
typedef float f32x4 __attribute__((ext_vector_type(4)));
typedef unsigned short u16x8 __attribute__((ext_vector_type(8)));
typedef unsigned short u16x4 __attribute__((ext_vector_type(4)));

static __device__ __forceinline__ unsigned short f2bf(float f) {
  unsigned int u = __builtin_bit_cast(unsigned int, f);
  u += 0x7fffu + ((u >> 16) & 1u);
  return (unsigned short)(u >> 16);
}
static __device__ __forceinline__ float bf2f(unsigned short h) {
  unsigned int u = ((unsigned int)h) << 16;
  return __builtin_bit_cast(float, u);
}
static __device__ __forceinline__ void async_cp16(void* lds, const void* g) {
  __builtin_amdgcn_global_load_lds((const __attribute__((address_space(1))) void*)g,
                                   (__attribute__((address_space(3))) void*)lds, 16, 0, 0);
}

// ---------------- x: fp32 -> bf16 ----------------
__global__ void k_cvt_x(const float* __restrict__ x, unsigned short* __restrict__ xb) {
  const size_t i = ((size_t)blockIdx.x * 256 + threadIdx.x) * 4;
  const float4 v = *(const float4*)(x + i);
  u16x4 o;
  o[0] = f2bf(v.x); o[1] = f2bf(v.y); o[2] = f2bf(v.z); o[3] = f2bf(v.w);
  *(u16x4*)(xb + i) = o;
}

// ------- weights: w (KxN fp32, row-major) -> Wt (NxK bf16) -------
__global__ void k_cvt_w(const float* __restrict__ wq, const float* __restrict__ wk,
                        const float* __restrict__ wv, const float* __restrict__ wo,
                        unsigned short* __restrict__ wqkvT, unsigned short* __restrict__ woT) {
  __shared__ float tile[64][65];
  const int z = blockIdx.z;
  const float* w = (z == 0) ? wq : (z == 1) ? wk : (z == 2) ? wv : wo;
  unsigned short* dst = (z < 3) ? (wqkvT + (size_t)z * DMODEL * DMODEL) : woT;
  const int n0 = blockIdx.x * 64, k0 = blockIdx.y * 64;
  for (int i = threadIdx.x; i < 4096; i += 256) {
    const int r = i >> 6, c = i & 63;
    tile[r][c] = w[(size_t)(k0 + r) * DMODEL + n0 + c];
  }
  __syncthreads();
  for (int i = threadIdx.x; i < 4096; i += 256) {
    const int r = i >> 6, c = i & 63;
    dst[(size_t)(n0 + r) * DMODEL + k0 + c] = f2bf(tile[c][r]);
  }
}

// ------------- GEMM: C[M x NOUT] = A[M x K] * Bt[NOUT x K]^T -------------
// m97-style: 128x128 tile, BK=32, 4 waves (2x2), global_load_lds width 16.
template <int NOUT, bool F32OUT>
__global__ __launch_bounds__(256) void k_gemm(const unsigned short* __restrict__ A,
                                              const unsigned short* __restrict__ Bt,
                                              void* __restrict__ Cout) {
  constexpr int K = DMODEL;
  __shared__ unsigned short Al[128 * 32];
  __shared__ unsigned short Bl[128 * 32];
  const int tid = threadIdx.x;
  const int lane = tid & 63, wid = tid >> 6;
  const int wm = wid >> 1, wn = wid & 1;
  const int tm = blockIdx.y * 128, tn = blockIdx.x * 128;
  const int fr = lane & 15, fq = lane >> 4;

  f32x4 acc[4][4];
#pragma unroll
  for (int i = 0; i < 4; ++i)
#pragma unroll
    for (int j = 0; j < 4; ++j) acc[i][j] = (f32x4){0.f, 0.f, 0.f, 0.f};

  // staging geometry: lane's slot byte offset o = wid*2048 + i*1024 + lane*16
  const int o0 = wid * 2048 + lane * 16;
  const int row0 = o0 >> 6;            // tile row (64B per row)
  const int ce0 = (o0 & 63) >> 1;      // col element within 32

  for (int kk = 0; kk < K; kk += 32) {
    async_cp16((char*)Al + wid * 2048,        A + (size_t)(tm + row0) * K + kk + ce0);
    async_cp16((char*)Al + wid * 2048 + 1024, A + (size_t)(tm + row0 + 16) * K + kk + ce0);
    async_cp16((char*)Bl + wid * 2048,        Bt + (size_t)(tn + row0) * K + kk + ce0);
    async_cp16((char*)Bl + wid * 2048 + 1024, Bt + (size_t)(tn + row0 + 16) * K + kk + ce0);
    __syncthreads();
    bf16x8 af[4], bf[4];
#pragma unroll
    for (int mi = 0; mi < 4; ++mi)
      af[mi] = *(const bf16x8*)(Al + (wm * 64 + mi * 16 + fr) * 32 + fq * 8);
#pragma unroll
    for (int ni = 0; ni < 4; ++ni)
      bf[ni] = *(const bf16x8*)(Bl + (wn * 64 + ni * 16 + fr) * 32 + fq * 8);
#pragma unroll
    for (int mi = 0; mi < 4; ++mi)
#pragma unroll
      for (int ni = 0; ni < 4; ++ni)
        acc[mi][ni] = __builtin_amdgcn_mfma_f32_16x16x32_bf16(af[mi], bf[ni], acc[mi][ni], 0, 0, 0);
    __syncthreads();
  }

#pragma unroll
  for (int mi = 0; mi < 4; ++mi) {
    const int row = tm + wm * 64 + mi * 16 + fq * 4;
#pragma unroll
    for (int ni = 0; ni < 4; ++ni) {
      const int col = tn + wn * 64 + ni * 16 + fr;
      if constexpr (F32OUT) {
        float* C = (float*)Cout;
#pragma unroll
        for (int r = 0; r < 4; ++r) C[(size_t)(row + r) * NOUT + col] = acc[mi][ni][r];
      } else {
        unsigned short* C = (unsigned short*)Cout;
#pragma unroll
        for (int r = 0; r < 4; ++r) C[(size_t)(row + r) * NOUT + col] = f2bf(acc[mi][ni][r]);
      }
    }
  }
}

// ------------- RoPE + relayout: qkv [8192][3072] -> qr/kr/vr (B,H,S,HD) -------------
__global__ void k_rope(const unsigned short* __restrict__ qkv, const float* __restrict__ fc,
                       const float* __restrict__ fs, unsigned short* __restrict__ qr,
                       unsigned short* __restrict__ kr, unsigned short* __restrict__ vr) {
  const int idx = blockIdx.x * 256 + threadIdx.x;  // < 8192*512
  const int row = idx >> 9;                        // b*S + s
  const int rem = idx & 511;
  const int h = rem >> 5, pr = rem & 31;
  const int s = row & (SEQ - 1), b = row >> 10;
  const size_t src = (size_t)row * NQKV + h * HDIM + 2 * pr;
  const size_t dst = ((size_t)(b * NHEAD + h) * SEQ + s) * HDIM + 2 * pr;
  const float c = fc[s * 32 + pr], sn = fs[s * 32 + pr];
  float tr = bf2f(qkv[src]), ti = bf2f(qkv[src + 1]);
  qr[dst] = f2bf(tr * c - ti * sn);
  qr[dst + 1] = f2bf(tr * sn + ti * c);
  tr = bf2f(qkv[src + DMODEL]); ti = bf2f(qkv[src + DMODEL + 1]);
  kr[dst] = f2bf(tr * c - ti * sn);
  kr[dst + 1] = f2bf(tr * sn + ti * c);
  *(unsigned int*)(vr + dst) = *(const unsigned int*)(qkv + src + 2 * DMODEL);
}

// ------------- flash attention, block-causal (BS=8) -------------
// grid (16 q-tiles, 128 bh); 4 waves; each wave owns 16 q-rows.
__global__ __launch_bounds__(256) void k_attn(const unsigned short* __restrict__ qr,
                                              const unsigned short* __restrict__ kr,
                                              const unsigned short* __restrict__ vr,
                                              unsigned short* __restrict__ ao) {
  const int qt = blockIdx.x, bh = blockIdx.y;
  const int tid = threadIdx.x, lane = tid & 63, w = tid >> 6;
  const int fr = lane & 15, fq = lane >> 4;
  __shared__ unsigned short Kt[64][72];        // K tile row-major, padded
  __shared__ unsigned short Vt[64][72];        // V tile transposed [d][k], padded
  __shared__ unsigned short Pl[4][16][72];     // per-wave P tile
  const size_t base = (size_t)bh * SEQ * HDIM;

  const int qrow = qt * 64 + w * 16 + fr;
  const bf16x8 qf0 = *(const bf16x8*)(qr + base + (size_t)qrow * HDIM + fq * 8);
  const bf16x8 qf1 = *(const bf16x8*)(qr + base + (size_t)qrow * HDIM + 32 + fq * 8);

  f32x4 oacc[4];
  float mprev[4], lsum[4];
#pragma unroll
  for (int i = 0; i < 4; ++i) { oacc[i] = (f32x4){0.f, 0.f, 0.f, 0.f}; mprev[i] = -3.0e38f; lsum[i] = 0.f; }

  const int rl = tid >> 2;        // staging row 0..63
  const int cl = (tid & 3) * 16;  // staging col 0/16/32/48

  for (int kt = 0; kt <= qt; ++kt) {
    __syncthreads();
    // stage K (row-major) and V (transposed)
    const unsigned short* kg = kr + base + (size_t)(kt * 64 + rl) * HDIM + cl;
    *(u16x8*)&Kt[rl][cl] = *(const u16x8*)kg;
    *(u16x8*)&Kt[rl][cl + 8] = *(const u16x8*)(kg + 8);
    const unsigned short* vg = vr + base + (size_t)(kt * 64 + rl) * HDIM + cl;
    const u16x8 v0 = *(const u16x8*)vg, v1 = *(const u16x8*)(vg + 8);
#pragma unroll
    for (int j = 0; j < 8; ++j) { Vt[cl + j][rl] = v0[j]; Vt[cl + 8 + j][rl] = v1[j]; }
    __syncthreads();

    // S = Q K^T
    f32x4 sc[4];
#pragma unroll
    for (int kb = 0; kb < 4; ++kb) {
      const bf16x8 k0 = *(const bf16x8*)&Kt[kb * 16 + fr][fq * 8];
      const bf16x8 k1 = *(const bf16x8*)&Kt[kb * 16 + fr][32 + fq * 8];
      sc[kb] = __builtin_amdgcn_mfma_f32_16x16x32_bf16(qf0, k0, (f32x4){0.f, 0.f, 0.f, 0.f}, 0, 0, 0);
      sc[kb] = __builtin_amdgcn_mfma_f32_16x16x32_bf16(qf1, k1, sc[kb], 0, 0, 0);
    }
    if (kt == qt) {  // diagonal tile: mask k-blocks above q-block (8-granular)
#pragma unroll
      for (int kb = 0; kb < 4; ++kb)
#pragma unroll
        for (int r = 0; r < 4; ++r)
          if (((kb * 16 + fr) >> 3) > ((w * 16 + fq * 4 + r) >> 3)) sc[kb][r] = -3.0e38f;
    }
    // online softmax over the 64 cols (rows live on 16-lane groups)
#pragma unroll
    for (int r = 0; r < 4; ++r) {
      float mx = fmaxf(fmaxf(sc[0][r], sc[1][r]), fmaxf(sc[2][r], sc[3][r]));
#pragma unroll
      for (int o = 1; o < 16; o <<= 1) mx = fmaxf(mx, __shfl_xor(mx, o));
      const float mnew = fmaxf(mprev[r], mx);
      const float corr = exp2f((mprev[r] - mnew) * SCALE_LOG2E);
      float rs = 0.f;
#pragma unroll
      for (int kb = 0; kb < 4; ++kb) {
        const float p = exp2f((sc[kb][r] - mnew) * SCALE_LOG2E);
        sc[kb][r] = p; rs += p;
      }
#pragma unroll
      for (int o = 1; o < 16; o <<= 1) rs += __shfl_xor(rs, o);
      lsum[r] = lsum[r] * corr + rs;
      mprev[r] = mnew;
#pragma unroll
      for (int db = 0; db < 4; ++db) oacc[db][r] *= corr;
    }
    // P -> LDS (per-wave), then PV
#pragma unroll
    for (int kb = 0; kb < 4; ++kb)
#pragma unroll
      for (int r = 0; r < 4; ++r)
        Pl[w][fq * 4 + r][kb * 16 + fr] = f2bf(sc[kb][r]);
    asm volatile("s_waitcnt lgkmcnt(0)" ::: "memory");
    __builtin_amdgcn_sched_barrier(0);
    const bf16x8 pf0 = *(const bf16x8*)&Pl[w][fr][fq * 8];
    const bf16x8 pf1 = *(const bf16x8*)&Pl[w][fr][32 + fq * 8];
#pragma unroll
    for (int db = 0; db < 4; ++db) {
      const bf16x8 vf0 = *(const bf16x8*)&Vt[db * 16 + fr][fq * 8];
      const bf16x8 vf1 = *(const bf16x8*)&Vt[db * 16 + fr][32 + fq * 8];
      oacc[db] = __builtin_amdgcn_mfma_f32_16x16x32_bf16(pf0, vf0, oacc[db], 0, 0, 0);
      oacc[db] = __builtin_amdgcn_mfma_f32_16x16x32_bf16(pf1, vf1, oacc[db], 0, 0, 0);
    }
  }
  // epilogue: O/l -> attn_out (b, s, h*64+hd) bf16
  const int b = bh >> 4, h = bh & 15;
#pragma unroll
  for (int db = 0; db < 4; ++db)
#pragma unroll
    for (int r = 0; r < 4; ++r) {
      const int qg = qt * 64 + w * 16 + fq * 4 + r;
      ao[((size_t)(b * SEQ + qg)) * DMODEL + h * HDIM + db * 16 + fr] = f2bf(oacc[db][r] / lsum[r]);
    }
}

extern "C" void kernel_launch(void* const* d_in, const int* in_sizes, int n_in,
                              void* d_out, int out_size, void* d_ws, size_t ws_size,
                              hipStream_t stream) {
  (void)in_sizes; (void)n_in; (void)out_size; (void)ws_size;
  const float* x = (const float*)d_in[0];
  const float* wq = (const float*)d_in[1];
  const float* wk = (const float*)d_in[2];
  const float* wv = (const float*)d_in[3];
  const float* wo = (const float*)d_in[4];
  const float* fc = (const float*)d_in[5];
  const float* fs = (const float*)d_in[6];
  float* out = (float*)d_out;

  // workspace carve (bf16 elems): 120 MB total
  unsigned short* xb = (unsigned short*)d_ws;                       // 8192x1024
  unsigned short* wqkvT = xb + (size_t)MROWS * DMODEL;              // 3072x1024
  unsigned short* woT = wqkvT + (size_t)NQKV * DMODEL;              // 1024x1024
  unsigned short* qrb = woT + (size_t)DMODEL * DMODEL;              // (B,H,S,HD)
  unsigned short* krb = qrb + (size_t)MROWS * DMODEL;
  unsigned short* vrb = krb + (size_t)MROWS * DMODEL;
  unsigned short* qkvr = vrb + (size_t)MROWS * DMODEL;              // 8192x3072
  unsigned short* aob = qkvr;                                       // reuse (qkv raw dead after rope)

  k_cvt_x<<<MROWS * DMODEL / 1024, 256, 0, stream>>>(x, xb);
  k_cvt_w<<<dim3(16, 16, 4), 256, 0, stream>>>(wq, wk, wv, wo, wqkvT, woT);
  k_gemm<NQKV, false><<<dim3(NQKV / 128, MROWS / 128), 256, 0, stream>>>(xb, wqkvT, qkvr);
  k_rope<<<MROWS * 512 / 256, 256, 0, stream>>>(qkvr, fc, fs, qrb, krb, vrb);
  k_attn<<<dim3(16, BATCH * NHEAD), 256, 0, stream>>>(qrb, krb, vrb, aob);
  k_gemm<DMODEL, true><<<dim3(DMODEL / 128, MROWS / 128), 256, 0, stream>>>(aob, woT, out);
}

// Round 6
// 274.950 us; speedup vs baseline: 1.2530x; 1.2530x over previous
//
#include <hip/hip_runtime.h>
#include <stdint.h>

#define BATCH 8
#define SEQ 1024
#define DMODEL 1024
#define NHEAD 16
#define HDIM 64
#define MROWS (BATCH * SEQ)   // 8192
#define NQKV (3 * DMODEL)     // 3072
// (1/sqrt(64)) * log2(e)
#define SCALE_LOG2E 0.18033688011112043f

typedef __bf16 bf16x8 __attribute__((ext_vector_type(8)));
typedef float f32x4 __attribute__((ext_vector_type(4)));
typedef unsigned short u16x8 __attribute__((ext_vector_type(8)));
typedef unsigned short u16x4 __attribute__((ext_vector_type(4)));

static __device__ __forceinline__ unsigned short f2bf(float f) {
  unsigned int u = __builtin_bit_cast(unsigned int, f);
  u += 0x7fffu + ((u >> 16) & 1u);
  return (unsigned short)(u >> 16);
}
static __device__ __forceinline__ float bf2f(unsigned short h) {
  unsigned int u = ((unsigned int)h) << 16;
  return __builtin_bit_cast(float, u);
}
static __device__ __forceinline__ void async_cp16(void* lds, const void* g) {
  __builtin_amdgcn_global_load_lds((const __attribute__((address_space(1))) void*)g,
                                   (__attribute__((address_space(3))) void*)lds, 16, 0, 0);
}

// ---------------- x: fp32 -> bf16 ----------------
__global__ void k_cvt_x(const float* __restrict__ x, unsigned short* __restrict__ xb) {
  const size_t i = ((size_t)blockIdx.x * 256 + threadIdx.x) * 4;
  const float4 v = *(const float4*)(x + i);
  u16x4 o;
  o[0] = f2bf(v.x); o[1] = f2bf(v.y); o[2] = f2bf(v.z); o[3] = f2bf(v.w);
  *(u16x4*)(xb + i) = o;
}

// ------- weights: w (KxN fp32, row-major) -> Wt (NxK bf16) -------
__global__ void k_cvt_w(const float* __restrict__ wq, const float* __restrict__ wk,
                        const float* __restrict__ wv, const float* __restrict__ wo,
                        unsigned short* __restrict__ wqkvT, unsigned short* __restrict__ woT) {
  __shared__ float tile[64][65];
  const int z = blockIdx.z;
  const float* w = (z == 0) ? wq : (z == 1) ? wk : (z == 2) ? wv : wo;
  unsigned short* dst = (z < 3) ? (wqkvT + (size_t)z * DMODEL * DMODEL) : woT;
  const int n0 = blockIdx.x * 64, k0 = blockIdx.y * 64;
  for (int i = threadIdx.x; i < 4096; i += 256) {
    const int r = i >> 6, c = i & 63;
    tile[r][c] = w[(size_t)(k0 + r) * DMODEL + n0 + c];
  }
  __syncthreads();
  for (int i = threadIdx.x; i < 4096; i += 256) {
    const int r = i >> 6, c = i & 63;
    dst[(size_t)(n0 + r) * DMODEL + k0 + c] = f2bf(tile[c][r]);
  }
}

// ------------- GEMM: C[M x NOUT] = A[M x K] * Bt[NOUT x K]^T -------------
// m97-style: 128x128 tile, BK=32, 4 waves (2x2), global_load_lds width 16.
// 1D grid with XCD-aware swizzle.
template <int NOUT, bool F32OUT>
__global__ __launch_bounds__(256) void k_gemm(const unsigned short* __restrict__ A,
                                              const unsigned short* __restrict__ Bt,
                                              void* __restrict__ Cout) {
  constexpr int K = DMODEL;
  constexpr int GX = NOUT / 128;
  __shared__ unsigned short Al[128 * 32];
  __shared__ unsigned short Bl[128 * 32];
  const int nwg = gridDim.x;
  const int o = blockIdx.x;
  const int t = (o & 7) * (nwg >> 3) + (o >> 3);
  const int tm = (t / GX) * 128, tn = (t % GX) * 128;
  const int tid = threadIdx.x;
  const int lane = tid & 63, wid = tid >> 6;
  const int wm = wid >> 1, wn = wid & 1;
  const int fr = lane & 15, fq = lane >> 4;

  f32x4 acc[4][4];
#pragma unroll
  for (int i = 0; i < 4; ++i)
#pragma unroll
    for (int j = 0; j < 4; ++j) acc[i][j] = (f32x4){0.f, 0.f, 0.f, 0.f};

  const int o0 = wid * 2048 + lane * 16;
  const int row0 = o0 >> 6;
  const int ce0 = (o0 & 63) >> 1;

  for (int kk = 0; kk < K; kk += 32) {
    async_cp16((char*)Al + wid * 2048,        A + (size_t)(tm + row0) * K + kk + ce0);
    async_cp16((char*)Al + wid * 2048 + 1024, A + (size_t)(tm + row0 + 16) * K + kk + ce0);
    async_cp16((char*)Bl + wid * 2048,        Bt + (size_t)(tn + row0) * K + kk + ce0);
    async_cp16((char*)Bl + wid * 2048 + 1024, Bt + (size_t)(tn + row0 + 16) * K + kk + ce0);
    __syncthreads();
    bf16x8 af[4], bf[4];
#pragma unroll
    for (int mi = 0; mi < 4; ++mi)
      af[mi] = *(const bf16x8*)(Al + (wm * 64 + mi * 16 + fr) * 32 + fq * 8);
#pragma unroll
    for (int ni = 0; ni < 4; ++ni)
      bf[ni] = *(const bf16x8*)(Bl + (wn * 64 + ni * 16 + fr) * 32 + fq * 8);
#pragma unroll
    for (int mi = 0; mi < 4; ++mi)
#pragma unroll
      for (int ni = 0; ni < 4; ++ni)
        acc[mi][ni] = __builtin_amdgcn_mfma_f32_16x16x32_bf16(af[mi], bf[ni], acc[mi][ni], 0, 0, 0);
    __syncthreads();
  }

#pragma unroll
  for (int mi = 0; mi < 4; ++mi) {
    const int row = tm + wm * 64 + mi * 16 + fq * 4;
#pragma unroll
    for (int ni = 0; ni < 4; ++ni) {
      const int col = tn + wn * 64 + ni * 16 + fr;
      if constexpr (F32OUT) {
        float* C = (float*)Cout;
#pragma unroll
        for (int r = 0; r < 4; ++r) C[(size_t)(row + r) * NOUT + col] = acc[mi][ni][r];
      } else {
        unsigned short* C = (unsigned short*)Cout;
#pragma unroll
        for (int r = 0; r < 4; ++r) C[(size_t)(row + r) * NOUT + col] = f2bf(acc[mi][ni][r]);
      }
    }
  }
}

// ------------- RoPE + relayout: qkv [8192][3072] -> qr/kr (B,H,S,HD) -------------
__global__ void k_rope(const unsigned short* __restrict__ qkv, const float* __restrict__ fc,
                       const float* __restrict__ fs, unsigned short* __restrict__ qr,
                       unsigned short* __restrict__ kr) {
  const int idx = blockIdx.x * 256 + threadIdx.x;  // < 8192*512
  const int row = idx >> 9;                        // b*S + s
  const int rem = idx & 511;
  const int h = rem >> 5, pr = rem & 31;
  const int s = row & (SEQ - 1), b = row >> 10;
  const size_t src = (size_t)row * NQKV + h * HDIM + 2 * pr;
  const size_t dst = ((size_t)(b * NHEAD + h) * SEQ + s) * HDIM + 2 * pr;
  const float c = fc[s * 32 + pr], sn = fs[s * 32 + pr];
  float tr = bf2f(qkv[src]), ti = bf2f(qkv[src + 1]);
  qr[dst] = f2bf(tr * c - ti * sn);
  qr[dst + 1] = f2bf(tr * sn + ti * c);
  tr = bf2f(qkv[src + DMODEL]); ti = bf2f(qkv[src + DMODEL + 1]);
  kr[dst] = f2bf(tr * c - ti * sn);
  kr[dst + 1] = f2bf(tr * sn + ti * c);
}

// ------------- V transpose: qkv V-part -> vt (B,H,HD,S) -------------
__global__ __launch_bounds__(256) void k_tv(const unsigned short* __restrict__ qkv,
                                            unsigned short* __restrict__ vt) {
  __shared__ unsigned short t[64][72];
  const int sb = blockIdx.x, bh = blockIdx.y;
  const int b = bh >> 4, h = bh & 15;
  const int tid = threadIdx.x;
  const int r0 = tid >> 3, c8 = (tid & 7) * 8;
#pragma unroll
  for (int p = 0; p < 2; ++p) {
    const int s = p * 32 + r0;
    *(u16x8*)&t[s][c8] =
        *(const u16x8*)(qkv + (size_t)(b * SEQ + sb * 64 + s) * NQKV + 2 * DMODEL + h * HDIM + c8);
  }
  __syncthreads();
#pragma unroll
  for (int p = 0; p < 2; ++p) {
    const int d = p * 32 + r0;
    u16x8 v;
#pragma unroll
    for (int j = 0; j < 8; ++j) v[j] = t[c8 + j][d];
    *(u16x8*)(vt + ((size_t)(bh * HDIM + d)) * SEQ + sb * 64 + c8) = v;
  }
}

// ------------- flash attention, block-causal (BS=8), swapped QK^T -------------
// 1D grid 2048 (XCD-swizzled, qt reversed); 4 waves; wave owns 16 q-rows.
__global__ __launch_bounds__(256) void k_attn(const unsigned short* __restrict__ qr,
                                              const unsigned short* __restrict__ kr,
                                              const unsigned short* __restrict__ vt,
                                              unsigned short* __restrict__ ao) {
  const int o = blockIdx.x, nwg = gridDim.x;
  const int t = (o & 7) * (nwg >> 3) + (o >> 3);
  const int qt = 15 - (t & 15);
  const int bh = t >> 4;
  const int tid = threadIdx.x, lane = tid & 63, w = tid >> 6;
  const int fr = lane & 15, fq = lane >> 4;
  __shared__ unsigned short Ks[2][4096];  // [64 k][64 d] bf16, XOR-swizzled rows of 128B
  __shared__ unsigned short Vs[2][4096];  // [64 d][64 k] bf16 (V^T), XOR-swizzled
  __shared__ unsigned short Ps[4][1024];  // per-wave P [16 q][64 k], XOR-swizzled
  const size_t base = (size_t)bh * SEQ * HDIM;
  const char* kgb = (const char*)(kr + base);
  const char* vgb = (const char*)(vt + base);

  const int qrow = qt * 64 + w * 16 + fr;
  const bf16x8 qf0 = *(const bf16x8*)(qr + base + (size_t)qrow * HDIM + fq * 8);
  const bf16x8 qf1 = *(const bf16x8*)(qr + base + (size_t)qrow * HDIM + 32 + fq * 8);
  const int qblk = (w * 16 + fr) >> 3;
  const int swz = (fr & 7) << 4;

  f32x4 oacc[4];
#pragma unroll
  for (int i = 0; i < 4; ++i) oacc[i] = (f32x4){0.f, 0.f, 0.f, 0.f};
  float m = -3.0e38f, l = 0.f;

  // stage one 64x64 tile pair (K and V^T) into buffer bb
  auto stage = [&](int kt, int bb) {
#pragma unroll
    for (int c = 0; c < 2; ++c) {
      const int dstb = c * 4096 + tid * 16;            // this lane's LDS byte slot
      const int row = dstb >> 7;                        // 0..63
      const int col = (dstb & 127) ^ ((row & 7) << 4);  // pre-swizzled source col
      char* kl = (char*)Ks[bb] + c * 4096 + (tid >> 6) * 1024;  // wave-uniform base
      char* vl = (char*)Vs[bb] + c * 4096 + (tid >> 6) * 1024;
      async_cp16(kl, kgb + (size_t)kt * 8192 + row * 128 + col);
      async_cp16(vl, vgb + (size_t)row * 2048 + kt * 128 + col);
    }
  };

  stage(0, 0);
  int buf = 0;
  for (int kt = 0; kt <= qt; ++kt) {
    const bool pre = (kt < qt);
    if (pre) {
      stage(kt + 1, buf ^ 1);
      asm volatile("s_waitcnt vmcnt(4)" ::: "memory");
    } else {
      asm volatile("s_waitcnt vmcnt(0)" ::: "memory");
    }
    __builtin_amdgcn_s_barrier();
    __builtin_amdgcn_sched_barrier(0);
    const char* Kb = (const char*)Ks[buf];
    const char* Vb = (const char*)Vs[buf];

    // S^T = K * Q^T  (A=K rows k, B=Q cols q) -> lane owns q=fr, k=16kb+4fq+r
    f32x4 sc[4];
#pragma unroll
    for (int kb = 0; kb < 4; ++kb) {
      const int rowb = (16 * kb + fr) * 128;
      const bf16x8 k0 = *(const bf16x8*)(Kb + rowb + ((16 * fq) ^ swz));
      const bf16x8 k1 = *(const bf16x8*)(Kb + rowb + ((64 + 16 * fq) ^ swz));
      sc[kb] = __builtin_amdgcn_mfma_f32_16x16x32_bf16(k0, qf0, (f32x4){0.f, 0.f, 0.f, 0.f}, 0, 0, 0);
      sc[kb] = __builtin_amdgcn_mfma_f32_16x16x32_bf16(k1, qf1, sc[kb], 0, 0, 0);
    }
    if (kt == qt) {  // diagonal: mask whole k-8-blocks (r-independent)
#pragma unroll
      for (int kb = 0; kb < 4; ++kb)
        if (2 * kb + (fq >> 1) > qblk) sc[kb] = (f32x4){-3.0e38f, -3.0e38f, -3.0e38f, -3.0e38f};
    }
    // lane-local softmax over 16 values + 2-shuffle reduce across 4 lane-groups
    float pmax = sc[0][0];
#pragma unroll
    for (int kb = 0; kb < 4; ++kb)
#pragma unroll
      for (int r = 0; r < 4; ++r) pmax = fmaxf(pmax, sc[kb][r]);
    pmax = fmaxf(pmax, __shfl_xor(pmax, 16));
    pmax = fmaxf(pmax, __shfl_xor(pmax, 32));
    const float mnew = fmaxf(m, pmax);
    const float corr = __builtin_amdgcn_exp2f((m - mnew) * SCALE_LOG2E);
    m = mnew;
    float rs = 0.f;
#pragma unroll
    for (int kb = 0; kb < 4; ++kb)
#pragma unroll
      for (int r = 0; r < 4; ++r) {
        const float p = __builtin_amdgcn_exp2f((sc[kb][r] - mnew) * SCALE_LOG2E);
        sc[kb][r] = p;
        rs += p;
      }
    rs += __shfl_xor(rs, 16);
    rs += __shfl_xor(rs, 32);
    l = l * corr + rs;
#pragma unroll
    for (int db = 0; db < 4; ++db) oacc[db] *= corr;
    // P -> per-wave LDS (row-major [q][k], swizzled), vector b64 writes
#pragma unroll
    for (int kb = 0; kb < 4; ++kb) {
      u16x4 pv;
#pragma unroll
      for (int r = 0; r < 4; ++r) pv[r] = f2bf(sc[kb][r]);
      *(u16x4*)((char*)Ps[w] + fr * 128 + ((32 * kb + 8 * fq) ^ swz)) = pv;
    }
    asm volatile("s_waitcnt lgkmcnt(0)" ::: "memory");
    __builtin_amdgcn_sched_barrier(0);
    // O^T += V^T * P^T : A=V^T rows d, B=P cols q (row-major P rows)
    const bf16x8 pf0 = *(const bf16x8*)((const char*)Ps[w] + fr * 128 + ((16 * fq) ^ swz));
    const bf16x8 pf1 = *(const bf16x8*)((const char*)Ps[w] + fr * 128 + ((64 + 16 * fq) ^ swz));
#pragma unroll
    for (int db = 0; db < 4; ++db) {
      const int rowb = (16 * db + fr) * 128;
      const bf16x8 v0 = *(const bf16x8*)(Vb + rowb + ((16 * fq) ^ swz));
      const bf16x8 v1 = *(const bf16x8*)(Vb + rowb + ((64 + 16 * fq) ^ swz));
      oacc[db] = __builtin_amdgcn_mfma_f32_16x16x32_bf16(v0, pf0, oacc[db], 0, 0, 0);
      oacc[db] = __builtin_amdgcn_mfma_f32_16x16x32_bf16(v1, pf1, oacc[db], 0, 0, 0);
    }
    asm volatile("s_waitcnt lgkmcnt(0)" ::: "memory");
    __builtin_amdgcn_sched_barrier(0);
    __builtin_amdgcn_s_barrier();
    buf ^= 1;
  }
  // epilogue: O = O^T^T / l -> ao (b, s, h*64+d) bf16
  const float inv = 1.f / l;
  const int b = bh >> 4, h = bh & 15;
  const int qg = qt * 64 + w * 16 + fr;
#pragma unroll
  for (int db = 0; db < 4; ++db) {
    u16x4 ov;
#pragma unroll
    for (int r = 0; r < 4; ++r) ov[r] = f2bf(oacc[db][r] * inv);
    *(u16x4*)(ao + (size_t)(b * SEQ + qg) * DMODEL + h * HDIM + 16 * db + 4 * fq) = ov;
  }
}

extern "C" void kernel_launch(void* const* d_in, const int* in_sizes, int n_in,
                              void* d_out, int out_size, void* d_ws, size_t ws_size,
                              hipStream_t stream) {
  (void)in_sizes; (void)n_in; (void)out_size; (void)ws_size;
  const float* x = (const float*)d_in[0];
  const float* wq = (const float*)d_in[1];
  const float* wk = (const float*)d_in[2];
  const float* wv = (const float*)d_in[3];
  const float* wo = (const float*)d_in[4];
  const float* fc = (const float*)d_in[5];
  const float* fs = (const float*)d_in[6];
  float* out = (float*)d_out;

  unsigned short* xb = (unsigned short*)d_ws;                       // 8192x1024
  unsigned short* wqkvT = xb + (size_t)MROWS * DMODEL;              // 3072x1024
  unsigned short* woT = wqkvT + (size_t)NQKV * DMODEL;              // 1024x1024
  unsigned short* qrb = woT + (size_t)DMODEL * DMODEL;              // (B,H,S,HD)
  unsigned short* krb = qrb + (size_t)MROWS * DMODEL;
  unsigned short* vtb = krb + (size_t)MROWS * DMODEL;               // (B,H,HD,S)
  unsigned short* qkvr = vtb + (size_t)MROWS * DMODEL;              // 8192x3072
  unsigned short* aob = qkvr;                                       // reuse after k_tv consumed V

  k_cvt_x<<<MROWS * DMODEL / 1024, 256, 0, stream>>>(x, xb);
  k_cvt_w<<<dim3(16, 16, 4), 256, 0, stream>>>(wq, wk, wv, wo, wqkvT, woT);
  k_gemm<NQKV, false><<<(NQKV / 128) * (MROWS / 128), 256, 0, stream>>>(xb, wqkvT, qkvr);
  k_rope<<<MROWS * 512 / 256, 256, 0, stream>>>(qkvr, fc, fs, qrb, krb);
  k_tv<<<dim3(16, BATCH * NHEAD), 256, 0, stream>>>(qkvr, vtb);
  k_attn<<<16 * BATCH * NHEAD, 256, 0, stream>>>(qrb, krb, vtb, aob);
  k_gemm<DMODEL, true><<<(DMODEL / 128) * (MROWS / 128), 256, 0, stream>>>(aob, woT, out);
}

// Round 7
// 265.364 us; speedup vs baseline: 1.2983x; 1.0361x over previous
//
#include <hip/hip_runtime.h>
#include <stdint.h>

#define BATCH 8
#define SEQ 1024
#define DMODEL 1024
#define NHEAD 16
#define HDIM 64
#define MROWS (BATCH * SEQ)   // 8192
#define NQKV (3 * DMODEL)     // 3072
// (1/sqrt(64)) * log2(e)
#define SCALE_LOG2E 0.18033688011112043f

typedef __bf16 bf16x8 __attribute__((ext_vector_type(8)));
typedef float f32x4 __attribute__((ext_vector_type(4)));
typedef unsigned short u16x8 __attribute__((ext_vector_type(8)));
typedef unsigned short u16x4 __attribute__((ext_vector_type(4)));

static __device__ __forceinline__ unsigned short f2bf(float f) {
  unsigned int u = __builtin_bit_cast(unsigned int, f);
  u += 0x7fffu + ((u >> 16) & 1u);
  return (unsigned short)(u >> 16);
}
static __device__ __forceinline__ float bf2f(unsigned short h) {
  unsigned int u = ((unsigned int)h) << 16;
  return __builtin_bit_cast(float, u);
}
static __device__ __forceinline__ void async_cp16(void* lds, const void* g) {
  __builtin_amdgcn_global_load_lds((const __attribute__((address_space(1))) void*)g,
                                   (__attribute__((address_space(3))) void*)lds, 16, 0, 0);
}

// ---------------- x: fp32 -> bf16 ----------------
__global__ void k_cvt_x(const float* __restrict__ x, unsigned short* __restrict__ xb) {
  const size_t i = ((size_t)blockIdx.x * 256 + threadIdx.x) * 4;
  const float4 v = *(const float4*)(x + i);
  u16x4 o;
  o[0] = f2bf(v.x); o[1] = f2bf(v.y); o[2] = f2bf(v.z); o[3] = f2bf(v.w);
  *(u16x4*)(xb + i) = o;
}

// ------- weights: w (KxN fp32, row-major) -> Wt (NxK bf16) -------
__global__ void k_cvt_w(const float* __restrict__ wq, const float* __restrict__ wk,
                        const float* __restrict__ wv, const float* __restrict__ wo,
                        unsigned short* __restrict__ wqkvT, unsigned short* __restrict__ woT) {
  __shared__ float tile[64][65];
  const int z = blockIdx.z;
  const float* w = (z == 0) ? wq : (z == 1) ? wk : (z == 2) ? wv : wo;
  unsigned short* dst = (z < 3) ? (wqkvT + (size_t)z * DMODEL * DMODEL) : woT;
  const int n0 = blockIdx.x * 64, k0 = blockIdx.y * 64;
  for (int i = threadIdx.x; i < 4096; i += 256) {
    const int r = i >> 6, c = i & 63;
    tile[r][c] = w[(size_t)(k0 + r) * DMODEL + n0 + c];
  }
  __syncthreads();
  for (int i = threadIdx.x; i < 4096; i += 256) {
    const int r = i >> 6, c = i & 63;
    dst[(size_t)(n0 + r) * DMODEL + k0 + c] = f2bf(tile[c][r]);
  }
}

// ------------- GEMM: C[M x NOUT] = A[M x K] * Bt[NOUT x K]^T -------------
// m97-style: 128x128 tile, BK=32, 4 waves (2x2), global_load_lds width 16.
template <int NOUT, bool F32OUT>
__global__ __launch_bounds__(256) void k_gemm(const unsigned short* __restrict__ A,
                                              const unsigned short* __restrict__ Bt,
                                              void* __restrict__ Cout) {
  constexpr int K = DMODEL;
  constexpr int GX = NOUT / 128;
  __shared__ unsigned short Al[128 * 32];
  __shared__ unsigned short Bl[128 * 32];
  const int nwg = gridDim.x;
  const int o = blockIdx.x;
  const int t = (o & 7) * (nwg >> 3) + (o >> 3);
  const int tm = (t / GX) * 128, tn = (t % GX) * 128;
  const int tid = threadIdx.x;
  const int lane = tid & 63, wid = tid >> 6;
  const int wm = wid >> 1, wn = wid & 1;
  const int fr = lane & 15, fq = lane >> 4;

  f32x4 acc[4][4];
#pragma unroll
  for (int i = 0; i < 4; ++i)
#pragma unroll
    for (int j = 0; j < 4; ++j) acc[i][j] = (f32x4){0.f, 0.f, 0.f, 0.f};

  const int o0 = wid * 2048 + lane * 16;
  const int row0 = o0 >> 6;
  const int ce0 = (o0 & 63) >> 1;

  for (int kk = 0; kk < K; kk += 32) {
    async_cp16((char*)Al + wid * 2048,        A + (size_t)(tm + row0) * K + kk + ce0);
    async_cp16((char*)Al + wid * 2048 + 1024, A + (size_t)(tm + row0 + 16) * K + kk + ce0);
    async_cp16((char*)Bl + wid * 2048,        Bt + (size_t)(tn + row0) * K + kk + ce0);
    async_cp16((char*)Bl + wid * 2048 + 1024, Bt + (size_t)(tn + row0 + 16) * K + kk + ce0);
    __syncthreads();
    bf16x8 af[4], bf[4];
#pragma unroll
    for (int mi = 0; mi < 4; ++mi)
      af[mi] = *(const bf16x8*)(Al + (wm * 64 + mi * 16 + fr) * 32 + fq * 8);
#pragma unroll
    for (int ni = 0; ni < 4; ++ni)
      bf[ni] = *(const bf16x8*)(Bl + (wn * 64 + ni * 16 + fr) * 32 + fq * 8);
#pragma unroll
    for (int mi = 0; mi < 4; ++mi)
#pragma unroll
      for (int ni = 0; ni < 4; ++ni)
        acc[mi][ni] = __builtin_amdgcn_mfma_f32_16x16x32_bf16(af[mi], bf[ni], acc[mi][ni], 0, 0, 0);
    __syncthreads();
  }

#pragma unroll
  for (int mi = 0; mi < 4; ++mi) {
    const int row = tm + wm * 64 + mi * 16 + fq * 4;
#pragma unroll
    for (int ni = 0; ni < 4; ++ni) {
      const int col = tn + wn * 64 + ni * 16 + fr;
      if constexpr (F32OUT) {
        float* C = (float*)Cout;
#pragma unroll
        for (int r = 0; r < 4; ++r) C[(size_t)(row + r) * NOUT + col] = acc[mi][ni][r];
      } else {
        unsigned short* C = (unsigned short*)Cout;
#pragma unroll
        for (int r = 0; r < 4; ++r) C[(size_t)(row + r) * NOUT + col] = f2bf(acc[mi][ni][r]);
      }
    }
  }
}

// ------------- QKV GEMM with fused RoPE + relayout epilogue -------------
// Same m97-style K-loop as k_gemm<NQKV,false>; epilogue writes:
//   q cols (0..1023)    -> rope -> qr (B,H,S,HD)
//   k cols (1024..2047) -> rope -> kr (B,H,S,HD)
//   v cols (2048..3071) -> transposed -> vt (B,H,HD,S)
// RoPE pair (hd, hd^1) lives in lanes (fr, fr^1) -> one __shfl_xor per elem,
// applied to the fp32 accumulator (pre-bf16-round).
__global__ __launch_bounds__(256) void k_gemm_qkv(const unsigned short* __restrict__ A,
                                                  const unsigned short* __restrict__ Bt,
                                                  const float* __restrict__ fc,
                                                  const float* __restrict__ fs,
                                                  unsigned short* __restrict__ qr,
                                                  unsigned short* __restrict__ kr,
                                                  unsigned short* __restrict__ vt) {
  constexpr int K = DMODEL;
  constexpr int GX = NQKV / 128;
  __shared__ unsigned short Al[128 * 32];
  __shared__ unsigned short Bl[128 * 32];
  const int nwg = gridDim.x;
  const int o = blockIdx.x;
  const int t = (o & 7) * (nwg >> 3) + (o >> 3);
  const int tm = (t / GX) * 128, tn = (t % GX) * 128;
  const int tid = threadIdx.x;
  const int lane = tid & 63, wid = tid >> 6;
  const int wm = wid >> 1, wn = wid & 1;
  const int fr = lane & 15, fq = lane >> 4;

  f32x4 acc[4][4];
#pragma unroll
  for (int i = 0; i < 4; ++i)
#pragma unroll
    for (int j = 0; j < 4; ++j) acc[i][j] = (f32x4){0.f, 0.f, 0.f, 0.f};

  const int o0 = wid * 2048 + lane * 16;
  const int row0 = o0 >> 6;
  const int ce0 = (o0 & 63) >> 1;

  for (int kk = 0; kk < K; kk += 32) {
    async_cp16((char*)Al + wid * 2048,        A + (size_t)(tm + row0) * K + kk + ce0);
    async_cp16((char*)Al + wid * 2048 + 1024, A + (size_t)(tm + row0 + 16) * K + kk + ce0);
    async_cp16((char*)Bl + wid * 2048,        Bt + (size_t)(tn + row0) * K + kk + ce0);
    async_cp16((char*)Bl + wid * 2048 + 1024, Bt + (size_t)(tn + row0 + 16) * K + kk + ce0);
    __syncthreads();
    bf16x8 af[4], bf[4];
#pragma unroll
    for (int mi = 0; mi < 4; ++mi)
      af[mi] = *(const bf16x8*)(Al + (wm * 64 + mi * 16 + fr) * 32 + fq * 8);
#pragma unroll
    for (int ni = 0; ni < 4; ++ni)
      bf[ni] = *(const bf16x8*)(Bl + (wn * 64 + ni * 16 + fr) * 32 + fq * 8);
#pragma unroll
    for (int mi = 0; mi < 4; ++mi)
#pragma unroll
      for (int ni = 0; ni < 4; ++ni)
        acc[mi][ni] = __builtin_amdgcn_mfma_f32_16x16x32_bf16(af[mi], bf[ni], acc[mi][ni], 0, 0, 0);
    __syncthreads();
  }

  // ---- fused epilogue ----
  const int typ = tn >> 10;                  // 0=q, 1=k, 2=v (block-uniform)
  const int hh = ((tn & 1023) >> 6) + wn;    // head index (block cols = 2 heads)
  if (typ == 2) {
#pragma unroll
    for (int mi = 0; mi < 4; ++mi) {
      const int rowb = tm + wm * 64 + mi * 16 + fq * 4;
      const int b = rowb >> 10, s0 = rowb & 1023;
#pragma unroll
      for (int ni = 0; ni < 4; ++ni) {
        const int hd = ni * 16 + fr;
        u16x4 ov;
#pragma unroll
        for (int r = 0; r < 4; ++r) ov[r] = f2bf(acc[mi][ni][r]);
        *(u16x4*)(vt + ((size_t)((b * 16 + hh) * 64 + hd)) * SEQ + s0) = ov;
      }
    }
  } else {
    unsigned short* dst = (typ == 0) ? qr : kr;
    const float sgn = (fr & 1) ? 1.0f : -1.0f;
#pragma unroll
    for (int mi = 0; mi < 4; ++mi) {
      const int rowb = tm + wm * 64 + mi * 16 + fq * 4;
      const int b = rowb >> 10, s0 = rowb & 1023;
#pragma unroll
      for (int ni = 0; ni < 4; ++ni) {
        const int hd = ni * 16 + fr;
        const int pr = ni * 8 + (fr >> 1);
#pragma unroll
        for (int r = 0; r < 4; ++r) {
          const float a = acc[mi][ni][r];
          const float p = __shfl_xor(a, 1);
          const float c = fc[(s0 + r) * 32 + pr];
          const float sn = fs[(s0 + r) * 32 + pr];
          dst[((size_t)((b * 16 + hh) * SEQ) + s0 + r) * HDIM + hd] = f2bf(a * c + sgn * (p * sn));
        }
      }
    }
  }
}

// ------------- flash attention, block-causal (BS=8), swapped QK^T -------------
// 1D grid 2048 (XCD-swizzled, qt reversed); 4 waves; wave owns 16 q-rows.
__global__ __launch_bounds__(256) void k_attn(const unsigned short* __restrict__ qr,
                                              const unsigned short* __restrict__ kr,
                                              const unsigned short* __restrict__ vt,
                                              unsigned short* __restrict__ ao) {
  const int o = blockIdx.x, nwg = gridDim.x;
  const int t = (o & 7) * (nwg >> 3) + (o >> 3);
  const int qt = 15 - (t & 15);
  const int bh = t >> 4;
  const int tid = threadIdx.x, lane = tid & 63, w = tid >> 6;
  const int fr = lane & 15, fq = lane >> 4;
  __shared__ unsigned short Ks[2][4096];  // [64 k][64 d] bf16, XOR-swizzled rows of 128B
  __shared__ unsigned short Vs[2][4096];  // [64 d][64 k] bf16 (V^T), XOR-swizzled
  __shared__ unsigned short Ps[4][1024];  // per-wave P [16 q][64 k], XOR-swizzled
  const size_t base = (size_t)bh * SEQ * HDIM;
  const char* kgb = (const char*)(kr + base);
  const char* vgb = (const char*)(vt + base);

  const int qrow = qt * 64 + w * 16 + fr;
  const bf16x8 qf0 = *(const bf16x8*)(qr + base + (size_t)qrow * HDIM + fq * 8);
  const bf16x8 qf1 = *(const bf16x8*)(qr + base + (size_t)qrow * HDIM + 32 + fq * 8);
  const int qblk = (w * 16 + fr) >> 3;
  const int swz = (fr & 7) << 4;

  f32x4 oacc[4];
#pragma unroll
  for (int i = 0; i < 4; ++i) oacc[i] = (f32x4){0.f, 0.f, 0.f, 0.f};
  float m = -3.0e38f, l = 0.f;

  auto stage = [&](int kt, int bb) {
#pragma unroll
    for (int c = 0; c < 2; ++c) {
      const int dstb = c * 4096 + tid * 16;
      const int row = dstb >> 7;
      const int col = (dstb & 127) ^ ((row & 7) << 4);
      char* kl = (char*)Ks[bb] + c * 4096 + (tid >> 6) * 1024;
      char* vl = (char*)Vs[bb] + c * 4096 + (tid >> 6) * 1024;
      async_cp16(kl, kgb + (size_t)kt * 8192 + row * 128 + col);
      async_cp16(vl, vgb + (size_t)row * 2048 + kt * 128 + col);
    }
  };

  stage(0, 0);
  int buf = 0;
  for (int kt = 0; kt <= qt; ++kt) {
    const bool pre = (kt < qt);
    if (pre) {
      stage(kt + 1, buf ^ 1);
      asm volatile("s_waitcnt vmcnt(4)" ::: "memory");
    } else {
      asm volatile("s_waitcnt vmcnt(0)" ::: "memory");
    }
    __builtin_amdgcn_s_barrier();
    __builtin_amdgcn_sched_barrier(0);
    const char* Kb = (const char*)Ks[buf];
    const char* Vb = (const char*)Vs[buf];

    f32x4 sc[4];
#pragma unroll
    for (int kb = 0; kb < 4; ++kb) {
      const int rowb = (16 * kb + fr) * 128;
      const bf16x8 k0 = *(const bf16x8*)(Kb + rowb + ((16 * fq) ^ swz));
      const bf16x8 k1 = *(const bf16x8*)(Kb + rowb + ((64 + 16 * fq) ^ swz));
      sc[kb] = __builtin_amdgcn_mfma_f32_16x16x32_bf16(k0, qf0, (f32x4){0.f, 0.f, 0.f, 0.f}, 0, 0, 0);
      sc[kb] = __builtin_amdgcn_mfma_f32_16x16x32_bf16(k1, qf1, sc[kb], 0, 0, 0);
    }
    if (kt == qt) {
#pragma unroll
      for (int kb = 0; kb < 4; ++kb)
        if (2 * kb + (fq >> 1) > qblk) sc[kb] = (f32x4){-3.0e38f, -3.0e38f, -3.0e38f, -3.0e38f};
    }
    float pmax = sc[0][0];
#pragma unroll
    for (int kb = 0; kb < 4; ++kb)
#pragma unroll
      for (int r = 0; r < 4; ++r) pmax = fmaxf(pmax, sc[kb][r]);
    pmax = fmaxf(pmax, __shfl_xor(pmax, 16));
    pmax = fmaxf(pmax, __shfl_xor(pmax, 32));
    const float mnew = fmaxf(m, pmax);
    const float corr = __builtin_amdgcn_exp2f((m - mnew) * SCALE_LOG2E);
    m = mnew;
    float rs = 0.f;
#pragma unroll
    for (int kb = 0; kb < 4; ++kb)
#pragma unroll
      for (int r = 0; r < 4; ++r) {
        const float p = __builtin_amdgcn_exp2f((sc[kb][r] - mnew) * SCALE_LOG2E);
        sc[kb][r] = p;
        rs += p;
      }
    rs += __shfl_xor(rs, 16);
    rs += __shfl_xor(rs, 32);
    l = l * corr + rs;
#pragma unroll
    for (int db = 0; db < 4; ++db) oacc[db] *= corr;
#pragma unroll
    for (int kb = 0; kb < 4; ++kb) {
      u16x4 pv;
#pragma unroll
      for (int r = 0; r < 4; ++r) pv[r] = f2bf(sc[kb][r]);
      *(u16x4*)((char*)Ps[w] + fr * 128 + ((32 * kb + 8 * fq) ^ swz)) = pv;
    }
    asm volatile("s_waitcnt lgkmcnt(0)" ::: "memory");
    __builtin_amdgcn_sched_barrier(0);
    const bf16x8 pf0 = *(const bf16x8*)((const char*)Ps[w] + fr * 128 + ((16 * fq) ^ swz));
    const bf16x8 pf1 = *(const bf16x8*)((const char*)Ps[w] + fr * 128 + ((64 + 16 * fq) ^ swz));
#pragma unroll
    for (int db = 0; db < 4; ++db) {
      const int rowb = (16 * db + fr) * 128;
      const bf16x8 v0 = *(const bf16x8*)(Vb + rowb + ((16 * fq) ^ swz));
      const bf16x8 v1 = *(const bf16x8*)(Vb + rowb + ((64 + 16 * fq) ^ swz));
      oacc[db] = __builtin_amdgcn_mfma_f32_16x16x32_bf16(v0, pf0, oacc[db], 0, 0, 0);
      oacc[db] = __builtin_amdgcn_mfma_f32_16x16x32_bf16(v1, pf1, oacc[db], 0, 0, 0);
    }
    asm volatile("s_waitcnt lgkmcnt(0)" ::: "memory");
    __builtin_amdgcn_sched_barrier(0);
    __builtin_amdgcn_s_barrier();
    buf ^= 1;
  }
  const float inv = 1.f / l;
  const int b = bh >> 4, h = bh & 15;
  const int qg = qt * 64 + w * 16 + fr;
#pragma unroll
  for (int db = 0; db < 4; ++db) {
    u16x4 ov;
#pragma unroll
    for (int r = 0; r < 4; ++r) ov[r] = f2bf(oacc[db][r] * inv);
    *(u16x4*)(ao + (size_t)(b * SEQ + qg) * DMODEL + h * HDIM + 16 * db + 4 * fq) = ov;
  }
}

extern "C" void kernel_launch(void* const* d_in, const int* in_sizes, int n_in,
                              void* d_out, int out_size, void* d_ws, size_t ws_size,
                              hipStream_t stream) {
  (void)in_sizes; (void)n_in; (void)out_size; (void)ws_size;
  const float* x = (const float*)d_in[0];
  const float* wq = (const float*)d_in[1];
  const float* wk = (const float*)d_in[2];
  const float* wv = (const float*)d_in[3];
  const float* wo = (const float*)d_in[4];
  const float* fc = (const float*)d_in[5];
  const float* fs = (const float*)d_in[6];
  float* out = (float*)d_out;

  unsigned short* xb = (unsigned short*)d_ws;                       // 8192x1024 (A for QKV gemm)
  unsigned short* wqkvT = xb + (size_t)MROWS * DMODEL;              // 3072x1024
  unsigned short* woT = wqkvT + (size_t)NQKV * DMODEL;              // 1024x1024
  unsigned short* qrb = woT + (size_t)DMODEL * DMODEL;              // (B,H,S,HD)
  unsigned short* krb = qrb + (size_t)MROWS * DMODEL;
  unsigned short* vtb = krb + (size_t)MROWS * DMODEL;               // (B,H,HD,S)
  unsigned short* aob = xb;                                         // xb dead after QKV gemm

  k_cvt_x<<<MROWS * DMODEL / 1024, 256, 0, stream>>>(x, xb);
  k_cvt_w<<<dim3(16, 16, 4), 256, 0, stream>>>(wq, wk, wv, wo, wqkvT, woT);
  k_gemm_qkv<<<(NQKV / 128) * (MROWS / 128), 256, 0, stream>>>(xb, wqkvT, fc, fs, qrb, krb, vtb);
  k_attn<<<16 * BATCH * NHEAD, 256, 0, stream>>>(qrb, krb, vtb, aob);
  k_gemm<DMODEL, true><<<(DMODEL / 128) * (MROWS / 128), 256, 0, stream>>>(aob, woT, out);
}

// Round 9
// 257.742 us; speedup vs baseline: 1.3366x; 1.0296x over previous
//
#include <hip/hip_runtime.h>
#include <stdint.h>

#define BATCH 8
#define SEQ 1024
#define DMODEL 1024
#define NHEAD 16
#define HDIM 64
#define MROWS (BATCH * SEQ)   // 8192
#define NQKV (3 * DMODEL)     // 3072
// (1/sqrt(64)) * log2(e)
#define SCALE_LOG2E 0.18033688011112043f

typedef __bf16 bf16x8 __attribute__((ext_vector_type(8)));
typedef float f32x4 __attribute__((ext_vector_type(4)));
typedef unsigned short u16x8 __attribute__((ext_vector_type(8)));
typedef unsigned short u16x4 __attribute__((ext_vector_type(4)));

static __device__ __forceinline__ unsigned short f2bf(float f) {
  unsigned int u = __builtin_bit_cast(unsigned int, f);
  u += 0x7fffu + ((u >> 16) & 1u);
  return (unsigned short)(u >> 16);
}
static __device__ __forceinline__ float bf2f(unsigned short h) {
  unsigned int u = ((unsigned int)h) << 16;
  return __builtin_bit_cast(float, u);
}
static __device__ __forceinline__ void async_cp16(void* lds, const void* g) {
  __builtin_amdgcn_global_load_lds((const __attribute__((address_space(1))) void*)g,
                                   (__attribute__((address_space(3))) void*)lds, 16, 0, 0);
}

// ---------------- x: fp32 -> bf16 ----------------
__global__ void k_cvt_x(const float* __restrict__ x, unsigned short* __restrict__ xb) {
  const size_t i = ((size_t)blockIdx.x * 256 + threadIdx.x) * 4;
  const float4 v = *(const float4*)(x + i);
  u16x4 o;
  o[0] = f2bf(v.x); o[1] = f2bf(v.y); o[2] = f2bf(v.z); o[3] = f2bf(v.w);
  *(u16x4*)(xb + i) = o;
}

// ------- rope tables: [s][pr] -> [pr][s] (for vectorized epilogue loads) -------
__global__ void k_tpose_tab(const float* __restrict__ fc, const float* __restrict__ fs,
                            float* __restrict__ fcT, float* __restrict__ fsT) {
  const int i = blockIdx.x * 256 + threadIdx.x;  // < 32768
  const int pr = i >> 10, s = i & 1023;
  fcT[i] = fc[s * 32 + pr];
  fsT[i] = fs[s * 32 + pr];
}

// ------- weights: w (KxN fp32, row-major) -> Wt (NxK bf16) -------
__global__ void k_cvt_w(const float* __restrict__ wq, const float* __restrict__ wk,
                        const float* __restrict__ wv, const float* __restrict__ wo,
                        unsigned short* __restrict__ wqkvT, unsigned short* __restrict__ woT) {
  __shared__ float tile[64][65];
  const int z = blockIdx.z;
  const float* w = (z == 0) ? wq : (z == 1) ? wk : (z == 2) ? wv : wo;
  unsigned short* dst = (z < 3) ? (wqkvT + (size_t)z * DMODEL * DMODEL) : woT;
  const int n0 = blockIdx.x * 64, k0 = blockIdx.y * 64;
  for (int i = threadIdx.x; i < 4096; i += 256) {
    const int r = i >> 6, c = i & 63;
    tile[r][c] = w[(size_t)(k0 + r) * DMODEL + n0 + c];
  }
  __syncthreads();
  for (int i = threadIdx.x; i < 4096; i += 256) {
    const int r = i >> 6, c = i & 63;
    dst[(size_t)(n0 + r) * DMODEL + k0 + c] = f2bf(tile[c][r]);
  }
}

// ------------- GEMM: C[M x NOUT] = A[M x K] * Bt[NOUT x K]^T -------------
// m97-style: 128x128 tile, BK=32, 4 waves (2x2), global_load_lds width 16.
template <int NOUT, bool F32OUT>
__global__ __launch_bounds__(256) void k_gemm(const unsigned short* __restrict__ A,
                                              const unsigned short* __restrict__ Bt,
                                              void* __restrict__ Cout) {
  constexpr int K = DMODEL;
  constexpr int GX = NOUT / 128;
  __shared__ unsigned short Al[128 * 32];
  __shared__ unsigned short Bl[128 * 32];
  const int nwg = gridDim.x;
  const int o = blockIdx.x;
  const int t = (o & 7) * (nwg >> 3) + (o >> 3);
  const int tm = (t / GX) * 128, tn = (t % GX) * 128;
  const int tid = threadIdx.x;
  const int lane = tid & 63, wid = tid >> 6;
  const int wm = wid >> 1, wn = wid & 1;
  const int fr = lane & 15, fq = lane >> 4;

  f32x4 acc[4][4];
#pragma unroll
  for (int i = 0; i < 4; ++i)
#pragma unroll
    for (int j = 0; j < 4; ++j) acc[i][j] = (f32x4){0.f, 0.f, 0.f, 0.f};

  const int o0 = wid * 2048 + lane * 16;
  const int row0 = o0 >> 6;
  const int ce0 = (o0 & 63) >> 1;

  for (int kk = 0; kk < K; kk += 32) {
    async_cp16((char*)Al + wid * 2048,        A + (size_t)(tm + row0) * K + kk + ce0);
    async_cp16((char*)Al + wid * 2048 + 1024, A + (size_t)(tm + row0 + 16) * K + kk + ce0);
    async_cp16((char*)Bl + wid * 2048,        Bt + (size_t)(tn + row0) * K + kk + ce0);
    async_cp16((char*)Bl + wid * 2048 + 1024, Bt + (size_t)(tn + row0 + 16) * K + kk + ce0);
    __syncthreads();
    bf16x8 af[4], bf[4];
#pragma unroll
    for (int mi = 0; mi < 4; ++mi)
      af[mi] = *(const bf16x8*)(Al + (wm * 64 + mi * 16 + fr) * 32 + fq * 8);
#pragma unroll
    for (int ni = 0; ni < 4; ++ni)
      bf[ni] = *(const bf16x8*)(Bl + (wn * 64 + ni * 16 + fr) * 32 + fq * 8);
#pragma unroll
    for (int mi = 0; mi < 4; ++mi)
#pragma unroll
      for (int ni = 0; ni < 4; ++ni)
        acc[mi][ni] = __builtin_amdgcn_mfma_f32_16x16x32_bf16(af[mi], bf[ni], acc[mi][ni], 0, 0, 0);
    __syncthreads();
  }

#pragma unroll
  for (int mi = 0; mi < 4; ++mi) {
    const int row = tm + wm * 64 + mi * 16 + fq * 4;
#pragma unroll
    for (int ni = 0; ni < 4; ++ni) {
      const int col = tn + wn * 64 + ni * 16 + fr;
      if constexpr (F32OUT) {
        float* C = (float*)Cout;
#pragma unroll
        for (int r = 0; r < 4; ++r) C[(size_t)(row + r) * NOUT + col] = acc[mi][ni][r];
      } else {
        unsigned short* C = (unsigned short*)Cout;
#pragma unroll
        for (int r = 0; r < 4; ++r) C[(size_t)(row + r) * NOUT + col] = f2bf(acc[mi][ni][r]);
      }
    }
  }
}

// ------------- QKV GEMM with fused RoPE + relayout epilogue -------------
//   q cols (0..1023)    -> rope -> qr (B,H,S,HD)
//   k cols (1024..2047) -> rope -> kr (B,H,S,HD)
//   v cols (2048..3071) -> transposed -> vt (B,H,HD,S)
// RoPE pair (hd, hd^1) lives in lanes (fr, fr^1) -> one __shfl_xor per elem.
// Tables pre-transposed to [pr][s] -> f32x4 loads over r.
// launch_bounds(...,3): force 3 waves/SIMD (K-loop needs 132 regs; round-7's
// 124 VGPR + 64 AGPR = 188 dropped us to 2 waves/SIMD, MfmaUtil 31->24).
__global__ __launch_bounds__(256, 3) void k_gemm_qkv(const unsigned short* __restrict__ A,
                                                     const unsigned short* __restrict__ Bt,
                                                     const float* __restrict__ fcT,
                                                     const float* __restrict__ fsT,
                                                     unsigned short* __restrict__ qr,
                                                     unsigned short* __restrict__ kr,
                                                     unsigned short* __restrict__ vt) {
  constexpr int K = DMODEL;
  constexpr int GX = NQKV / 128;
  __shared__ unsigned short Al[128 * 32];
  __shared__ unsigned short Bl[128 * 32];
  const int nwg = gridDim.x;
  const int o = blockIdx.x;
  const int t = (o & 7) * (nwg >> 3) + (o >> 3);
  const int tm = (t / GX) * 128, tn = (t % GX) * 128;
  const int tid = threadIdx.x;
  const int lane = tid & 63, wid = tid >> 6;
  const int wm = wid >> 1, wn = wid & 1;
  const int fr = lane & 15, fq = lane >> 4;

  f32x4 acc[4][4];
#pragma unroll
  for (int i = 0; i < 4; ++i)
#pragma unroll
    for (int j = 0; j < 4; ++j) acc[i][j] = (f32x4){0.f, 0.f, 0.f, 0.f};

  const int o0 = wid * 2048 + lane * 16;
  const int row0 = o0 >> 6;
  const int ce0 = (o0 & 63) >> 1;

  for (int kk = 0; kk < K; kk += 32) {
    async_cp16((char*)Al + wid * 2048,        A + (size_t)(tm + row0) * K + kk + ce0);
    async_cp16((char*)Al + wid * 2048 + 1024, A + (size_t)(tm + row0 + 16) * K + kk + ce0);
    async_cp16((char*)Bl + wid * 2048,        Bt + (size_t)(tn + row0) * K + kk + ce0);
    async_cp16((char*)Bl + wid * 2048 + 1024, Bt + (size_t)(tn + row0 + 16) * K + kk + ce0);
    __syncthreads();
    bf16x8 af[4], bf[4];
#pragma unroll
    for (int mi = 0; mi < 4; ++mi)
      af[mi] = *(const bf16x8*)(Al + (wm * 64 + mi * 16 + fr) * 32 + fq * 8);
#pragma unroll
    for (int ni = 0; ni < 4; ++ni)
      bf[ni] = *(const bf16x8*)(Bl + (wn * 64 + ni * 16 + fr) * 32 + fq * 8);
#pragma unroll
    for (int mi = 0; mi < 4; ++mi)
#pragma unroll
      for (int ni = 0; ni < 4; ++ni)
        acc[mi][ni] = __builtin_amdgcn_mfma_f32_16x16x32_bf16(af[mi], bf[ni], acc[mi][ni], 0, 0, 0);
    __syncthreads();
  }

  // ---- fused epilogue ----
  const int typ = tn >> 10;                  // 0=q, 1=k, 2=v (block-uniform)
  const int hh = ((tn & 1023) >> 6) + wn;    // head index (block cols = 2 heads)
  if (typ == 2) {
#pragma unroll
    for (int mi = 0; mi < 4; ++mi) {
      const int rowb = tm + wm * 64 + mi * 16 + fq * 4;
      const int b = rowb >> 10, s0 = rowb & 1023;
#pragma unroll
      for (int ni = 0; ni < 4; ++ni) {
        const int hd = ni * 16 + fr;
        u16x4 ov;
#pragma unroll
        for (int r = 0; r < 4; ++r) ov[r] = f2bf(acc[mi][ni][r]);
        *(u16x4*)(vt + ((size_t)((b * 16 + hh) * 64 + hd)) * SEQ + s0) = ov;
      }
    }
  } else {
    unsigned short* dst = (typ == 0) ? qr : kr;
    const float sgn = (fr & 1) ? 1.0f : -1.0f;
#pragma unroll
    for (int mi = 0; mi < 4; ++mi) {
      const int rowb = tm + wm * 64 + mi * 16 + fq * 4;
      const int b = rowb >> 10, s0 = rowb & 1023;
#pragma unroll
      for (int ni = 0; ni < 4; ++ni) {
        const int hd = ni * 16 + fr;
        const int pr = ni * 8 + (fr >> 1);
        const f32x4 cc = *(const f32x4*)(fcT + (pr << 10) + s0);
        const f32x4 ss = *(const f32x4*)(fsT + (pr << 10) + s0);
#pragma unroll
        for (int r = 0; r < 4; ++r) {
          const float a = acc[mi][ni][r];
          const float p = __shfl_xor(a, 1);
          dst[((size_t)((b * 16 + hh) * SEQ) + s0 + r) * HDIM + hd] = f2bf(a * cc[r] + sgn * (p * ss[r]));
        }
      }
    }
  }
}

// ------------- flash attention, block-causal (BS=8), swapped QK^T -------------
// 1D grid 2048 (XCD-swizzled, qt reversed); 4 waves; wave owns 16 q-rows.
__global__ __launch_bounds__(256) void k_attn(const unsigned short* __restrict__ qr,
                                              const unsigned short* __restrict__ kr,
                                              const unsigned short* __restrict__ vt,
                                              unsigned short* __restrict__ ao) {
  const int o = blockIdx.x, nwg = gridDim.x;
  const int t = (o & 7) * (nwg >> 3) + (o >> 3);
  const int qt = 15 - (t & 15);
  const int bh = t >> 4;
  const int tid = threadIdx.x, lane = tid & 63, w = tid >> 6;
  const int fr = lane & 15, fq = lane >> 4;
  __shared__ unsigned short Ks[2][4096];  // [64 k][64 d] bf16, XOR-swizzled rows of 128B
  __shared__ unsigned short Vs[2][4096];  // [64 d][64 k] bf16 (V^T), XOR-swizzled
  __shared__ unsigned short Ps[4][1024];  // per-wave P [16 q][64 k], XOR-swizzled
  const size_t base = (size_t)bh * SEQ * HDIM;
  const char* kgb = (const char*)(kr + base);
  const char* vgb = (const char*)(vt + base);

  const int qrow = qt * 64 + w * 16 + fr;
  const bf16x8 qf0 = *(const bf16x8*)(qr + base + (size_t)qrow * HDIM + fq * 8);
  const bf16x8 qf1 = *(const bf16x8*)(qr + base + (size_t)qrow * HDIM + 32 + fq * 8);
  const int qblk = (w * 16 + fr) >> 3;
  const int swz = (fr & 7) << 4;

  f32x4 oacc[4];
#pragma unroll
  for (int i = 0; i < 4; ++i) oacc[i] = (f32x4){0.f, 0.f, 0.f, 0.f};
  float m = -3.0e38f, l = 0.f;

  auto stage = [&](int kt, int bb) {
#pragma unroll
    for (int c = 0; c < 2; ++c) {
      const int dstb = c * 4096 + tid * 16;
      const int row = dstb >> 7;
      const int col = (dstb & 127) ^ ((row & 7) << 4);
      char* kl = (char*)Ks[bb] + c * 4096 + (tid >> 6) * 1024;
      char* vl = (char*)Vs[bb] + c * 4096 + (tid >> 6) * 1024;
      async_cp16(kl, kgb + (size_t)kt * 8192 + row * 128 + col);
      async_cp16(vl, vgb + (size_t)row * 2048 + kt * 128 + col);
    }
  };

  stage(0, 0);
  int buf = 0;
  for (int kt = 0; kt <= qt; ++kt) {
    const bool pre = (kt < qt);
    if (pre) {
      stage(kt + 1, buf ^ 1);
      asm volatile("s_waitcnt vmcnt(4)" ::: "memory");
    } else {
      asm volatile("s_waitcnt vmcnt(0)" ::: "memory");
    }
    __builtin_amdgcn_s_barrier();
    __builtin_amdgcn_sched_barrier(0);
    const char* Kb = (const char*)Ks[buf];
    const char* Vb = (const char*)Vs[buf];

    f32x4 sc[4];
#pragma unroll
    for (int kb = 0; kb < 4; ++kb) {
      const int rowb = (16 * kb + fr) * 128;
      const bf16x8 k0 = *(const bf16x8*)(Kb + rowb + ((16 * fq) ^ swz));
      const bf16x8 k1 = *(const bf16x8*)(Kb + rowb + ((64 + 16 * fq) ^ swz));
      sc[kb] = __builtin_amdgcn_mfma_f32_16x16x32_bf16(k0, qf0, (f32x4){0.f, 0.f, 0.f, 0.f}, 0, 0, 0);
      sc[kb] = __builtin_amdgcn_mfma_f32_16x16x32_bf16(k1, qf1, sc[kb], 0, 0, 0);
    }
    if (kt == qt) {
#pragma unroll
      for (int kb = 0; kb < 4; ++kb)
        if (2 * kb + (fq >> 1) > qblk) sc[kb] = (f32x4){-3.0e38f, -3.0e38f, -3.0e38f, -3.0e38f};
    }
    float pmax = sc[0][0];
#pragma unroll
    for (int kb = 0; kb < 4; ++kb)
#pragma unroll
      for (int r = 0; r < 4; ++r) pmax = fmaxf(pmax, sc[kb][r]);
    pmax = fmaxf(pmax, __shfl_xor(pmax, 16));
    pmax = fmaxf(pmax, __shfl_xor(pmax, 32));
    const float mnew = fmaxf(m, pmax);
    const float corr = __builtin_amdgcn_exp2f((m - mnew) * SCALE_LOG2E);
    m = mnew;
    float rs = 0.f;
#pragma unroll
    for (int kb = 0; kb < 4; ++kb)
#pragma unroll
      for (int r = 0; r < 4; ++r) {
        const float p = __builtin_amdgcn_exp2f((sc[kb][r] - mnew) * SCALE_LOG2E);
        sc[kb][r] = p;
        rs += p;
      }
    rs += __shfl_xor(rs, 16);
    rs += __shfl_xor(rs, 32);
    l = l * corr + rs;
#pragma unroll
    for (int db = 0; db < 4; ++db) oacc[db] *= corr;
#pragma unroll
    for (int kb = 0; kb < 4; ++kb) {
      u16x4 pv;
#pragma unroll
      for (int r = 0; r < 4; ++r) pv[r] = f2bf(sc[kb][r]);
      *(u16x4*)((char*)Ps[w] + fr * 128 + ((32 * kb + 8 * fq) ^ swz)) = pv;
    }
    asm volatile("s_waitcnt lgkmcnt(0)" ::: "memory");
    __builtin_amdgcn_sched_barrier(0);
    const bf16x8 pf0 = *(const bf16x8*)((const char*)Ps[w] + fr * 128 + ((16 * fq) ^ swz));
    const bf16x8 pf1 = *(const bf16x8*)((const char*)Ps[w] + fr * 128 + ((64 + 16 * fq) ^ swz));
#pragma unroll
    for (int db = 0; db < 4; ++db) {
      const int rowb = (16 * db + fr) * 128;
      const bf16x8 v0 = *(const bf16x8*)(Vb + rowb + ((16 * fq) ^ swz));
      const bf16x8 v1 = *(const bf16x8*)(Vb + rowb + ((64 + 16 * fq) ^ swz));
      oacc[db] = __builtin_amdgcn_mfma_f32_16x16x32_bf16(v0, pf0, oacc[db], 0, 0, 0);
      oacc[db] = __builtin_amdgcn_mfma_f32_16x16x32_bf16(v1, pf1, oacc[db], 0, 0, 0);
    }
    asm volatile("s_waitcnt lgkmcnt(0)" ::: "memory");
    __builtin_amdgcn_sched_barrier(0);
    __builtin_amdgcn_s_barrier();
    buf ^= 1;
  }
  const float inv = 1.f / l;
  const int b = bh >> 4, h = bh & 15;
  const int qg = qt * 64 + w * 16 + fr;
#pragma unroll
  for (int db = 0; db < 4; ++db) {
    u16x4 ov;
#pragma unroll
    for (int r = 0; r < 4; ++r) ov[r] = f2bf(oacc[db][r] * inv);
    *(u16x4*)(ao + (size_t)(b * SEQ + qg) * DMODEL + h * HDIM + 16 * db + 4 * fq) = ov;
  }
}

extern "C" void kernel_launch(void* const* d_in, const int* in_sizes, int n_in,
                              void* d_out, int out_size, void* d_ws, size_t ws_size,
                              hipStream_t stream) {
  (void)in_sizes; (void)n_in; (void)out_size; (void)ws_size;
  const float* x = (const float*)d_in[0];
  const float* wq = (const float*)d_in[1];
  const float* wk = (const float*)d_in[2];
  const float* wv = (const float*)d_in[3];
  const float* wo = (const float*)d_in[4];
  const float* fc = (const float*)d_in[5];
  const float* fs = (const float*)d_in[6];
  float* out = (float*)d_out;

  unsigned short* xb = (unsigned short*)d_ws;                       // 8192x1024 (A for QKV gemm)
  unsigned short* wqkvT = xb + (size_t)MROWS * DMODEL;              // 3072x1024
  unsigned short* woT = wqkvT + (size_t)NQKV * DMODEL;              // 1024x1024
  unsigned short* qrb = woT + (size_t)DMODEL * DMODEL;              // (B,H,S,HD)
  unsigned short* krb = qrb + (size_t)MROWS * DMODEL;
  unsigned short* vtb = krb + (size_t)MROWS * DMODEL;               // (B,H,HD,S)
  float* fcT = (float*)(vtb + (size_t)MROWS * DMODEL);              // [32][1024]
  float* fsT = fcT + 32 * SEQ;
  unsigned short* aob = xb;                                         // xb dead after QKV gemm

  k_cvt_x<<<MROWS * DMODEL / 1024, 256, 0, stream>>>(x, xb);
  k_tpose_tab<<<128, 256, 0, stream>>>(fc, fs, fcT, fsT);
  k_cvt_w<<<dim3(16, 16, 4), 256, 0, stream>>>(wq, wk, wv, wo, wqkvT, woT);
  k_gemm_qkv<<<(NQKV / 128) * (MROWS / 128), 256, 0, stream>>>(xb, wqkvT, fcT, fsT, qrb, krb, vtb);
  k_attn<<<16 * BATCH * NHEAD, 256, 0, stream>>>(qrb, krb, vtb, aob);
  k_gemm<DMODEL, true><<<(DMODEL / 128) * (MROWS / 128), 256, 0, stream>>>(aob, woT, out);
}

// Round 10
// 248.865 us; speedup vs baseline: 1.3843x; 1.0357x over previous
//
#include <hip/hip_runtime.h>
#include <stdint.h>

#define BATCH 8
#define SEQ 1024
#define DMODEL 1024
#define NHEAD 16
#define HDIM 64
#define MROWS (BATCH * SEQ)   // 8192
#define NQKV (3 * DMODEL)     // 3072
// (1/sqrt(64)) * log2(e)
#define SCALE_LOG2E 0.18033688011112043f

typedef __bf16 bf16x8 __attribute__((ext_vector_type(8)));
typedef float f32x4 __attribute__((ext_vector_type(4)));
typedef unsigned short u16x8 __attribute__((ext_vector_type(8)));
typedef unsigned short u16x4 __attribute__((ext_vector_type(4)));

static __device__ __forceinline__ unsigned short f2bf(float f) {
  unsigned int u = __builtin_bit_cast(unsigned int, f);
  u += 0x7fffu + ((u >> 16) & 1u);
  return (unsigned short)(u >> 16);
}
static __device__ __forceinline__ void async_cp16(void* lds, const void* g) {
  __builtin_amdgcn_global_load_lds((const __attribute__((address_space(1))) void*)g,
                                   (__attribute__((address_space(3))) void*)lds, 16, 0, 0);
}

// ------------- fused prep: x cast | weight transpose+cast | rope-table transpose -------------
// blocks [0,8192): x fp32->bf16 ; [8192,9216): weights ; [9216,9344): tables
__global__ __launch_bounds__(256) void k_prep(const float* __restrict__ x,
                                              const float* __restrict__ wq, const float* __restrict__ wk,
                                              const float* __restrict__ wv, const float* __restrict__ wo,
                                              const float* __restrict__ fc, const float* __restrict__ fs,
                                              unsigned short* __restrict__ xb,
                                              unsigned short* __restrict__ wqkvT,
                                              unsigned short* __restrict__ woT,
                                              float* __restrict__ fcT, float* __restrict__ fsT) {
  __shared__ float tile[64][65];
  const int bx = blockIdx.x;
  const int tid = threadIdx.x;
  if (bx < 8192) {
    const size_t i = ((size_t)bx * 256 + tid) * 4;
    const float4 v = *(const float4*)(x + i);
    u16x4 o;
    o[0] = f2bf(v.x); o[1] = f2bf(v.y); o[2] = f2bf(v.z); o[3] = f2bf(v.w);
    *(u16x4*)(xb + i) = o;
  } else if (bx < 9216) {
    const int idx = bx - 8192;
    const int z = idx >> 8;
    const float* w = (z == 0) ? wq : (z == 1) ? wk : (z == 2) ? wv : wo;
    unsigned short* dst = (z < 3) ? (wqkvT + (size_t)z * DMODEL * DMODEL) : woT;
    const int n0 = (idx & 15) * 64, k0 = ((idx >> 4) & 15) * 64;
    for (int i = tid; i < 4096; i += 256) {
      const int r = i >> 6, c = i & 63;
      tile[r][c] = w[(size_t)(k0 + r) * DMODEL + n0 + c];
    }
    __syncthreads();
    for (int i = tid; i < 4096; i += 256) {
      const int r = i >> 6, c = i & 63;
      dst[(size_t)(n0 + r) * DMODEL + k0 + c] = f2bf(tile[c][r]);
    }
  } else {
    const int i = (bx - 9216) * 256 + tid;  // < 32768
    const int pr = i >> 10, s = i & 1023;
    fcT[i] = fc[s * 32 + pr];
    fsT[i] = fs[s * 32 + pr];
  }
}

// ------------- GEMM: C[M x NOUT] = A[M x K] * Bt[NOUT x K]^T -------------
// m97-style: 128x128 tile, BK=32, 4 waves (2x2), global_load_lds width 16.
template <int NOUT, bool F32OUT>
__global__ __launch_bounds__(256) void k_gemm(const unsigned short* __restrict__ A,
                                              const unsigned short* __restrict__ Bt,
                                              void* __restrict__ Cout) {
  constexpr int K = DMODEL;
  constexpr int GX = NOUT / 128;
  __shared__ unsigned short Al[128 * 32];
  __shared__ unsigned short Bl[128 * 32];
  const int nwg = gridDim.x;
  const int o = blockIdx.x;
  const int t = (o & 7) * (nwg >> 3) + (o >> 3);
  const int tm = (t / GX) * 128, tn = (t % GX) * 128;
  const int tid = threadIdx.x;
  const int lane = tid & 63, wid = tid >> 6;
  const int wm = wid >> 1, wn = wid & 1;
  const int fr = lane & 15, fq = lane >> 4;

  f32x4 acc[4][4];
#pragma unroll
  for (int i = 0; i < 4; ++i)
#pragma unroll
    for (int j = 0; j < 4; ++j) acc[i][j] = (f32x4){0.f, 0.f, 0.f, 0.f};

  const int o0 = wid * 2048 + lane * 16;
  const int row0 = o0 >> 6;
  const int ce0 = (o0 & 63) >> 1;

  for (int kk = 0; kk < K; kk += 32) {
    async_cp16((char*)Al + wid * 2048,        A + (size_t)(tm + row0) * K + kk + ce0);
    async_cp16((char*)Al + wid * 2048 + 1024, A + (size_t)(tm + row0 + 16) * K + kk + ce0);
    async_cp16((char*)Bl + wid * 2048,        Bt + (size_t)(tn + row0) * K + kk + ce0);
    async_cp16((char*)Bl + wid * 2048 + 1024, Bt + (size_t)(tn + row0 + 16) * K + kk + ce0);
    __syncthreads();
    bf16x8 af[4], bf[4];
#pragma unroll
    for (int mi = 0; mi < 4; ++mi)
      af[mi] = *(const bf16x8*)(Al + (wm * 64 + mi * 16 + fr) * 32 + fq * 8);
#pragma unroll
    for (int ni = 0; ni < 4; ++ni)
      bf[ni] = *(const bf16x8*)(Bl + (wn * 64 + ni * 16 + fr) * 32 + fq * 8);
#pragma unroll
    for (int mi = 0; mi < 4; ++mi)
#pragma unroll
      for (int ni = 0; ni < 4; ++ni)
        acc[mi][ni] = __builtin_amdgcn_mfma_f32_16x16x32_bf16(af[mi], bf[ni], acc[mi][ni], 0, 0, 0);
    __syncthreads();
  }

#pragma unroll
  for (int mi = 0; mi < 4; ++mi) {
    const int row = tm + wm * 64 + mi * 16 + fq * 4;
#pragma unroll
    for (int ni = 0; ni < 4; ++ni) {
      const int col = tn + wn * 64 + ni * 16 + fr;
      if constexpr (F32OUT) {
        float* C = (float*)Cout;
#pragma unroll
        for (int r = 0; r < 4; ++r) C[(size_t)(row + r) * NOUT + col] = acc[mi][ni][r];
      } else {
        unsigned short* C = (unsigned short*)Cout;
#pragma unroll
        for (int r = 0; r < 4; ++r) C[(size_t)(row + r) * NOUT + col] = f2bf(acc[mi][ni][r]);
      }
    }
  }
}

// ------------- QKV GEMM with fused RoPE + relayout epilogue -------------
__global__ __launch_bounds__(256, 3) void k_gemm_qkv(const unsigned short* __restrict__ A,
                                                     const unsigned short* __restrict__ Bt,
                                                     const float* __restrict__ fcT,
                                                     const float* __restrict__ fsT,
                                                     unsigned short* __restrict__ qr,
                                                     unsigned short* __restrict__ kr,
                                                     unsigned short* __restrict__ vt) {
  constexpr int K = DMODEL;
  constexpr int GX = NQKV / 128;
  __shared__ unsigned short Al[128 * 32];
  __shared__ unsigned short Bl[128 * 32];
  const int nwg = gridDim.x;
  const int o = blockIdx.x;
  const int t = (o & 7) * (nwg >> 3) + (o >> 3);
  const int tm = (t / GX) * 128, tn = (t % GX) * 128;
  const int tid = threadIdx.x;
  const int lane = tid & 63, wid = tid >> 6;
  const int wm = wid >> 1, wn = wid & 1;
  const int fr = lane & 15, fq = lane >> 4;

  f32x4 acc[4][4];
#pragma unroll
  for (int i = 0; i < 4; ++i)
#pragma unroll
    for (int j = 0; j < 4; ++j) acc[i][j] = (f32x4){0.f, 0.f, 0.f, 0.f};

  const int o0 = wid * 2048 + lane * 16;
  const int row0 = o0 >> 6;
  const int ce0 = (o0 & 63) >> 1;

  for (int kk = 0; kk < K; kk += 32) {
    async_cp16((char*)Al + wid * 2048,        A + (size_t)(tm + row0) * K + kk + ce0);
    async_cp16((char*)Al + wid * 2048 + 1024, A + (size_t)(tm + row0 + 16) * K + kk + ce0);
    async_cp16((char*)Bl + wid * 2048,        Bt + (size_t)(tn + row0) * K + kk + ce0);
    async_cp16((char*)Bl + wid * 2048 + 1024, Bt + (size_t)(tn + row0 + 16) * K + kk + ce0);
    __syncthreads();
    bf16x8 af[4], bf[4];
#pragma unroll
    for (int mi = 0; mi < 4; ++mi)
      af[mi] = *(const bf16x8*)(Al + (wm * 64 + mi * 16 + fr) * 32 + fq * 8);
#pragma unroll
    for (int ni = 0; ni < 4; ++ni)
      bf[ni] = *(const bf16x8*)(Bl + (wn * 64 + ni * 16 + fr) * 32 + fq * 8);
#pragma unroll
    for (int mi = 0; mi < 4; ++mi)
#pragma unroll
      for (int ni = 0; ni < 4; ++ni)
        acc[mi][ni] = __builtin_amdgcn_mfma_f32_16x16x32_bf16(af[mi], bf[ni], acc[mi][ni], 0, 0, 0);
    __syncthreads();
  }

  // ---- fused epilogue ----
  const int typ = tn >> 10;                  // 0=q, 1=k, 2=v (block-uniform)
  const int hh = ((tn & 1023) >> 6) + wn;    // head index (block cols = 2 heads)
  if (typ == 2) {
#pragma unroll
    for (int mi = 0; mi < 4; ++mi) {
      const int rowb = tm + wm * 64 + mi * 16 + fq * 4;
      const int b = rowb >> 10, s0 = rowb & 1023;
#pragma unroll
      for (int ni = 0; ni < 4; ++ni) {
        const int hd = ni * 16 + fr;
        u16x4 ov;
#pragma unroll
        for (int r = 0; r < 4; ++r) ov[r] = f2bf(acc[mi][ni][r]);
        *(u16x4*)(vt + ((size_t)((b * 16 + hh) * 64 + hd)) * SEQ + s0) = ov;
      }
    }
  } else {
    unsigned short* dst = (typ == 0) ? qr : kr;
    const float sgn = (fr & 1) ? 1.0f : -1.0f;
#pragma unroll
    for (int mi = 0; mi < 4; ++mi) {
      const int rowb = tm + wm * 64 + mi * 16 + fq * 4;
      const int b = rowb >> 10, s0 = rowb & 1023;
#pragma unroll
      for (int ni = 0; ni < 4; ++ni) {
        const int hd = ni * 16 + fr;
        const int pr = ni * 8 + (fr >> 1);
        const f32x4 cc = *(const f32x4*)(fcT + (pr << 10) + s0);
        const f32x4 ss = *(const f32x4*)(fsT + (pr << 10) + s0);
#pragma unroll
        for (int r = 0; r < 4; ++r) {
          const float a = acc[mi][ni][r];
          const float p = __shfl_xor(a, 1);
          dst[((size_t)((b * 16 + hh) * SEQ) + s0 + r) * HDIM + hd] = f2bf(a * cc[r] + sgn * (p * ss[r]));
        }
      }
    }
  }
}

// ------------- flash attention, block-causal (BS=8), swapped QK^T -------------
// QBLK=128: 8 waves (512 thr), wave owns 16 q-rows; causal wave-skip (uniform).
// grid 1024 (XCD-swizzled, qt reversed).
__global__ __launch_bounds__(512) void k_attn(const unsigned short* __restrict__ qr,
                                              const unsigned short* __restrict__ kr,
                                              const unsigned short* __restrict__ vt,
                                              unsigned short* __restrict__ ao) {
  const int o = blockIdx.x, nwg = gridDim.x;
  const int t = (o & 7) * (nwg >> 3) + (o >> 3);
  const int qt2 = 7 - (t & 7);
  const int bh = t >> 3;
  const int tid = threadIdx.x, lane = tid & 63, w = tid >> 6;
  const int fr = lane & 15, fq = lane >> 4;
  __shared__ unsigned short Ks[2][4096];  // [64 k][64 d], XOR-swizzled 128B rows
  __shared__ unsigned short Vs[2][4096];  // [64 d][64 k] (V^T), XOR-swizzled
  __shared__ unsigned short Ps[8][1024];  // per-wave P [16 q][64 k], XOR-swizzled
  const size_t base = (size_t)bh * SEQ * HDIM;
  const char* kgb = (const char*)(kr + base);
  const char* vgb = (const char*)(vt + base);

  const int qmin = qt2 * 128 + w * 16;     // wave's first q-row
  const int qrow = qmin + fr;
  const bf16x8 qf0 = *(const bf16x8*)(qr + base + (size_t)qrow * HDIM + fq * 8);
  const bf16x8 qf1 = *(const bf16x8*)(qr + base + (size_t)qrow * HDIM + 32 + fq * 8);
  const int qblk8 = qrow >> 3;
  const int swz = (fr & 7) << 4;

  f32x4 oacc[4];
#pragma unroll
  for (int i = 0; i < 4; ++i) oacc[i] = (f32x4){0.f, 0.f, 0.f, 0.f};
  float m = -3.0e38f, l = 0.f;

  // 512 threads stage one 64x64 K tile + one V^T tile in a single pass
  auto stage = [&](int kt, int bb) {
    const int dstb = tid * 16;                        // 0..8191
    const int row = dstb >> 7;                        // 0..63
    const int col = (dstb & 127) ^ ((row & 7) << 4);  // pre-swizzled source col
    char* kl = (char*)Ks[bb] + (tid >> 6) * 1024;     // wave-uniform base
    char* vl = (char*)Vs[bb] + (tid >> 6) * 1024;
    async_cp16(kl, kgb + (size_t)kt * 8192 + row * 128 + col);
    async_cp16(vl, vgb + (size_t)row * 2048 + kt * 128 + col);
  };

  const int ktmax = 2 * qt2 + 1;
  stage(0, 0);
  int buf = 0;
  for (int kt = 0; kt <= ktmax; ++kt) {
    if (kt < ktmax) {
      stage(kt + 1, buf ^ 1);
      asm volatile("s_waitcnt vmcnt(2)" ::: "memory");
    } else {
      asm volatile("s_waitcnt vmcnt(0)" ::: "memory");
    }
    __builtin_amdgcn_s_barrier();
    __builtin_amdgcn_sched_barrier(0);
    const char* Kb = (const char*)Ks[buf];
    const char* Vb = (const char*)Vs[buf];

    // wave-uniform causal skip: wave needs tile iff kt*64 <= qmin+15
    if (kt * 64 <= qmin + 15) {
      // S^T = K * Q^T -> lane owns q=fr, k=16kb+4fq+r
      f32x4 sc[4];
#pragma unroll
      for (int kb = 0; kb < 4; ++kb) {
        const int rowb = (16 * kb + fr) * 128;
        const bf16x8 k0 = *(const bf16x8*)(Kb + rowb + ((16 * fq) ^ swz));
        const bf16x8 k1 = *(const bf16x8*)(Kb + rowb + ((64 + 16 * fq) ^ swz));
        sc[kb] = __builtin_amdgcn_mfma_f32_16x16x32_bf16(k0, qf0, (f32x4){0.f, 0.f, 0.f, 0.f}, 0, 0, 0);
        sc[kb] = __builtin_amdgcn_mfma_f32_16x16x32_bf16(k1, qf1, sc[kb], 0, 0, 0);
      }
      if (kt * 64 + 56 > qmin) {  // partial tile: mask k-8-blocks above q-8-block
#pragma unroll
        for (int kb = 0; kb < 4; ++kb)
          if (8 * kt + 2 * kb + (fq >> 1) > qblk8)
            sc[kb] = (f32x4){-3.0e38f, -3.0e38f, -3.0e38f, -3.0e38f};
      }
      // lane-local softmax + 2-shuffle reduce across 4 lane-groups
      float pmax = sc[0][0];
#pragma unroll
      for (int kb = 0; kb < 4; ++kb)
#pragma unroll
        for (int r = 0; r < 4; ++r) pmax = fmaxf(pmax, sc[kb][r]);
      pmax = fmaxf(pmax, __shfl_xor(pmax, 16));
      pmax = fmaxf(pmax, __shfl_xor(pmax, 32));
      const float mnew = fmaxf(m, pmax);
      const float corr = __builtin_amdgcn_exp2f((m - mnew) * SCALE_LOG2E);
      m = mnew;
      float rs = 0.f;
#pragma unroll
      for (int kb = 0; kb < 4; ++kb)
#pragma unroll
        for (int r = 0; r < 4; ++r) {
          const float p = __builtin_amdgcn_exp2f((sc[kb][r] - mnew) * SCALE_LOG2E);
          sc[kb][r] = p;
          rs += p;
        }
      rs += __shfl_xor(rs, 16);
      rs += __shfl_xor(rs, 32);
      l = l * corr + rs;
#pragma unroll
      for (int db = 0; db < 4; ++db) oacc[db] *= corr;
      // P -> per-wave LDS (row-major [q][k], swizzled)
#pragma unroll
      for (int kb = 0; kb < 4; ++kb) {
        u16x4 pv;
#pragma unroll
        for (int r = 0; r < 4; ++r) pv[r] = f2bf(sc[kb][r]);
        *(u16x4*)((char*)Ps[w] + fr * 128 + ((32 * kb + 8 * fq) ^ swz)) = pv;
      }
      asm volatile("s_waitcnt lgkmcnt(0)" ::: "memory");
      __builtin_amdgcn_sched_barrier(0);
      // O^T += V^T * P^T
      const bf16x8 pf0 = *(const bf16x8*)((const char*)Ps[w] + fr * 128 + ((16 * fq) ^ swz));
      const bf16x8 pf1 = *(const bf16x8*)((const char*)Ps[w] + fr * 128 + ((64 + 16 * fq) ^ swz));
#pragma unroll
      for (int db = 0; db < 4; ++db) {
        const int rowb = (16 * db + fr) * 128;
        const bf16x8 v0 = *(const bf16x8*)(Vb + rowb + ((16 * fq) ^ swz));
        const bf16x8 v1 = *(const bf16x8*)(Vb + rowb + ((64 + 16 * fq) ^ swz));
        oacc[db] = __builtin_amdgcn_mfma_f32_16x16x32_bf16(v0, pf0, oacc[db], 0, 0, 0);
        oacc[db] = __builtin_amdgcn_mfma_f32_16x16x32_bf16(v1, pf1, oacc[db], 0, 0, 0);
      }
      asm volatile("s_waitcnt lgkmcnt(0)" ::: "memory");
      __builtin_amdgcn_sched_barrier(0);
    }
    __builtin_amdgcn_s_barrier();
    buf ^= 1;
  }
  // epilogue
  const float inv = 1.f / l;
  const int b = bh >> 4, h = bh & 15;
#pragma unroll
  for (int db = 0; db < 4; ++db) {
    u16x4 ov;
#pragma unroll
    for (int r = 0; r < 4; ++r) ov[r] = f2bf(oacc[db][r] * inv);
    *(u16x4*)(ao + (size_t)(b * SEQ + qrow) * DMODEL + h * HDIM + 16 * db + 4 * fq) = ov;
  }
}

extern "C" void kernel_launch(void* const* d_in, const int* in_sizes, int n_in,
                              void* d_out, int out_size, void* d_ws, size_t ws_size,
                              hipStream_t stream) {
  (void)in_sizes; (void)n_in; (void)out_size; (void)ws_size;
  const float* x = (const float*)d_in[0];
  const float* wq = (const float*)d_in[1];
  const float* wk = (const float*)d_in[2];
  const float* wv = (const float*)d_in[3];
  const float* wo = (const float*)d_in[4];
  const float* fc = (const float*)d_in[5];
  const float* fs = (const float*)d_in[6];
  float* out = (float*)d_out;

  unsigned short* xb = (unsigned short*)d_ws;                       // 8192x1024 (A for QKV gemm)
  unsigned short* wqkvT = xb + (size_t)MROWS * DMODEL;              // 3072x1024
  unsigned short* woT = wqkvT + (size_t)NQKV * DMODEL;              // 1024x1024
  unsigned short* qrb = woT + (size_t)DMODEL * DMODEL;              // (B,H,S,HD)
  unsigned short* krb = qrb + (size_t)MROWS * DMODEL;
  unsigned short* vtb = krb + (size_t)MROWS * DMODEL;               // (B,H,HD,S)
  float* fcT = (float*)(vtb + (size_t)MROWS * DMODEL);              // [32][1024]
  float* fsT = fcT + 32 * SEQ;
  unsigned short* aob = xb;                                         // xb dead after QKV gemm

  k_prep<<<9344, 256, 0, stream>>>(x, wq, wk, wv, wo, fc, fs, xb, wqkvT, woT, fcT, fsT);
  k_gemm_qkv<<<(NQKV / 128) * (MROWS / 128), 256, 0, stream>>>(xb, wqkvT, fcT, fsT, qrb, krb, vtb);
  k_attn<<<8 * BATCH * NHEAD, 512, 0, stream>>>(qrb, krb, vtb, aob);
  k_gemm<DMODEL, true><<<(DMODEL / 128) * (MROWS / 128), 256, 0, stream>>>(aob, woT, out);
}